// Round 10
// baseline (393.745 us; speedup 1.0000x reference)
//
#include <hip/hip_runtime.h>
#include <hip/hip_bf16.h>

typedef __bf16 bfv8 __attribute__((ext_vector_type(8)));
typedef float f32x4 __attribute__((ext_vector_type(4)));
typedef unsigned int u32;

#define MFMA(a,b,c) __builtin_amdgcn_mfma_f32_16x16x32_bf16((a),(b),(c),0,0,0)

constexpr int XW_LD = 392;   // 384+8 pad

// Transposed bf16 weights: qT[col][k] = w_qkv[k][col], pT[col][k] = w_proj[k][col]
__global__ __launch_bounds__(256)
void prep_weights(const float* __restrict__ w_qkv, const float* __restrict__ w_proj,
                  unsigned short* __restrict__ qT, unsigned short* __restrict__ pT)
{
    int i = blockIdx.x * 256 + threadIdx.x;
    const int NQ = 1152 * 384;
    if (i < NQ) {
        int c = i / 384, k = i - c * 384;
        __bf16 h = (__bf16)w_qkv[k * 1152 + c];
        qT[i] = *(unsigned short*)&h;
    } else {
        int j = i - NQ;
        if (j < 384 * 384) {
            int c = j / 384, k = j - c * 384;
            __bf16 h = (__bf16)w_proj[k * 384 + c];
            pT[j] = *(unsigned short*)&h;
        }
    }
}

__device__ __forceinline__ u32 pkbf(float a, float b) {
    __bf16 x = (__bf16)a, y = (__bf16)b;
    unsigned short lo = *(unsigned short*)&x, hi = *(unsigned short*)&y;
    return ((u32)hi << 16) | lo;
}

// Universal D-frag -> A/B-frag converter (HW-verified rounds 3-9):
// dest lane (lg,lr) dword w <- lane (2*(lg&1)+(w>>1))*16+lr, packed dword (w&1),
// tile pair selected by lg&2.
__device__ __forceinline__ bfv8 conv_frag(u32 p00, u32 p01, u32 p10, u32 p11,
                                          int abase, bool selhi)
{
    union { u32 u[4]; bfv8 v; } cv;
    #pragma unroll
    for (int w = 0; w < 4; ++w) {
        const int addr = abase + (w >> 1) * 64;
        const int lo_ = __builtin_amdgcn_ds_bpermute(addr, (int)((w & 1) ? p01 : p00));
        const int hi_ = __builtin_amdgcn_ds_bpermute(addr, (int)((w & 1) ? p11 : p10));
        cv.u[w] = (u32)(selhi ? hi_ : lo_);
    }
    return cv.v;
}

// One WG (256 thr = 4 waves) per 8x8 window; wave owns 3 heads end-to-end.
// QKV computed as THREE sequential single-matrix passes (Q,K,V): peak live
// accumulators 32 regs instead of 96 -> fits the 170-reg budget at 3 waves/SIMD
// with NO scratch spill (R4/R9's hidden ~150MB spill). No setprio (unablated
// since R3; suspect it starves load-issuing waves).
// MFMA 16x16x32 layouts (m89/m92): a_frag lane(lg,lr) elem j = A[lr][k8+j];
// b_frag = B[k8+j][lr]; d lane reg r = D[lg*4+r][lr].
__global__ __launch_bounds__(256, 3)
void win_attn(const float* __restrict__ x,
              const float* __restrict__ b_qkv,
              const float* __restrict__ b_proj,
              const unsigned short* __restrict__ qT_,
              const unsigned short* __restrict__ pT_,
              float* __restrict__ out)
{
    __shared__ __bf16 sX[64 * XW_LD];   // 50176 B -> 3 WG/CU

    const __bf16* wqkvT  = (const __bf16*)qT_;
    const __bf16* wprojT = (const __bf16*)pT_;

    const int wid  = blockIdx.x;
    const int bb   = wid >> 6;
    const int wy   = (wid >> 3) & 7;
    const int wx   = wid & 7;
    const int tid  = threadIdx.x;
    const int lane = tid & 63;
    const int wv   = tid >> 6;          // wave 0..3
    const int lr   = lane & 15;
    const int lg   = lane >> 4;
    const int k8   = lg * 8;

    const size_t gbase = ((size_t)(bb * 64 + wy * 8) * 64 + wx * 8) * 384;

    // ---- stage x window -> sX bf16 ----
    {
        const float* xb = x + gbase;
        for (int i = tid; i < 64 * 96; i += 256) {
            int t  = i / 96;
            int c4 = (i - t * 96) * 4;
            const float4 v = *(const float4*)(xb + (size_t)((t >> 3) * 64 + (t & 7)) * 384 + c4);
            *(uint2*)&sX[t * XW_LD + c4] = make_uint2(pkbf(v.x, v.y), pkbf(v.z, v.w));
        }
    }
    __syncthreads();   // barrier 1

    const int   abase = ((lg & 1) * 32 + lr) * 4;
    const bool  selhi = (lg & 2) != 0;
    const float SC    = 0.17677669529663687f;   // 32^-0.5

    u32 opk[3][4][2][2];   // fully-static indices -> registers

    #pragma unroll
    for (int hl = 0; hl < 3; ++hl) {
        const int h  = wv * 3 + hl;
        const int cQ = h * 32, cK = cQ + 384, cV = cQ + 768;
        const __bf16* xp = &sX[lr * XW_LD + k8];

        u32 pkQ[2][4][2], pkK[2][4][2], pkV[4][2][2];

        // ---- pass 1: Q^T = mfma(Wq-frag, x-frag), swapped ----
        {
            f32x4 acc[2][4];
            #pragma unroll
            for (int a = 0; a < 2; ++a)
                #pragma unroll
                for (int b = 0; b < 4; ++b) acc[a][b] = f32x4{0,0,0,0};
            const __bf16* wp = wqkvT + (size_t)(cQ + lr) * 384 + k8;
            #pragma unroll 4
            for (int kk = 0; kk < 12; ++kk) {
                bfv8 xf[4], wf[2];
                #pragma unroll
                for (int t4 = 0; t4 < 4; ++t4) xf[t4] = *(const bfv8*)(xp + t4 * 16 * XW_LD + kk * 32);
                #pragma unroll
                for (int hdt = 0; hdt < 2; ++hdt) wf[hdt] = *(const bfv8*)(wp + (size_t)hdt * 16 * 384 + kk * 32);
                #pragma unroll
                for (int hdt = 0; hdt < 2; ++hdt)
                    #pragma unroll
                    for (int t4 = 0; t4 < 4; ++t4)
                        acc[hdt][t4] = MFMA(wf[hdt], xf[t4], acc[hdt][t4]);   // Q^T[hd][tok]
            }
            #pragma unroll
            for (int hdt = 0; hdt < 2; ++hdt) {
                float b0 = b_qkv[cQ + hdt * 16 + lg * 4 + 0];
                float b1 = b_qkv[cQ + hdt * 16 + lg * 4 + 1];
                float b2 = b_qkv[cQ + hdt * 16 + lg * 4 + 2];
                float b3 = b_qkv[cQ + hdt * 16 + lg * 4 + 3];
                #pragma unroll
                for (int t4 = 0; t4 < 4; ++t4) {
                    pkQ[hdt][t4][0] = pkbf((acc[hdt][t4][0] + b0) * SC, (acc[hdt][t4][1] + b1) * SC);
                    pkQ[hdt][t4][1] = pkbf((acc[hdt][t4][2] + b2) * SC, (acc[hdt][t4][3] + b3) * SC);
                }
            }
        }

        // ---- pass 2: K^T = mfma(Wk-frag, x-frag), swapped ----
        {
            f32x4 acc[2][4];
            #pragma unroll
            for (int a = 0; a < 2; ++a)
                #pragma unroll
                for (int b = 0; b < 4; ++b) acc[a][b] = f32x4{0,0,0,0};
            const __bf16* wp = wqkvT + (size_t)(cK + lr) * 384 + k8;
            #pragma unroll 4
            for (int kk = 0; kk < 12; ++kk) {
                bfv8 xf[4], wf[2];
                #pragma unroll
                for (int t4 = 0; t4 < 4; ++t4) xf[t4] = *(const bfv8*)(xp + t4 * 16 * XW_LD + kk * 32);
                #pragma unroll
                for (int hdt = 0; hdt < 2; ++hdt) wf[hdt] = *(const bfv8*)(wp + (size_t)hdt * 16 * 384 + kk * 32);
                #pragma unroll
                for (int hdt = 0; hdt < 2; ++hdt)
                    #pragma unroll
                    for (int t4 = 0; t4 < 4; ++t4)
                        acc[hdt][t4] = MFMA(wf[hdt], xf[t4], acc[hdt][t4]);   // K^T[hd][tok]
            }
            #pragma unroll
            for (int hdt = 0; hdt < 2; ++hdt) {
                float b0 = b_qkv[cK + hdt * 16 + lg * 4 + 0];
                float b1 = b_qkv[cK + hdt * 16 + lg * 4 + 1];
                float b2 = b_qkv[cK + hdt * 16 + lg * 4 + 2];
                float b3 = b_qkv[cK + hdt * 16 + lg * 4 + 3];
                #pragma unroll
                for (int t4 = 0; t4 < 4; ++t4) {
                    pkK[hdt][t4][0] = pkbf(acc[hdt][t4][0] + b0, acc[hdt][t4][1] + b1);
                    pkK[hdt][t4][1] = pkbf(acc[hdt][t4][2] + b2, acc[hdt][t4][3] + b3);
                }
            }
        }

        // ---- pass 3: V = mfma(x-frag, Wv-frag), normal ----
        {
            f32x4 acc[4][2];
            #pragma unroll
            for (int a = 0; a < 4; ++a)
                #pragma unroll
                for (int b = 0; b < 2; ++b) acc[a][b] = f32x4{0,0,0,0};
            const __bf16* wp = wqkvT + (size_t)(cV + lr) * 384 + k8;
            #pragma unroll 4
            for (int kk = 0; kk < 12; ++kk) {
                bfv8 xf[4], wf[2];
                #pragma unroll
                for (int t4 = 0; t4 < 4; ++t4) xf[t4] = *(const bfv8*)(xp + t4 * 16 * XW_LD + kk * 32);
                #pragma unroll
                for (int hdt = 0; hdt < 2; ++hdt) wf[hdt] = *(const bfv8*)(wp + (size_t)hdt * 16 * 384 + kk * 32);
                #pragma unroll
                for (int t4 = 0; t4 < 4; ++t4)
                    #pragma unroll
                    for (int hdt = 0; hdt < 2; ++hdt)
                        acc[t4][hdt] = MFMA(xf[t4], wf[hdt], acc[t4][hdt]);   // V[tok][hd]
            }
            #pragma unroll
            for (int hdt = 0; hdt < 2; ++hdt) {
                const float bv = b_qkv[cV + hdt * 16 + lr];
                #pragma unroll
                for (int t4 = 0; t4 < 4; ++t4) {
                    pkV[t4][hdt][0] = pkbf(acc[t4][hdt][0] + bv, acc[t4][hdt][1] + bv);
                    pkV[t4][hdt][1] = pkbf(acc[t4][hdt][2] + bv, acc[t4][hdt][3] + bv);
                }
            }
        }

        // ---- S^T = mfma(K-frag, Q-frag): lane holds S[q=qt*16+lr][key=kt*16+lg*4+r] ----
        bfv8 Qf[4];
        #pragma unroll
        for (int qt = 0; qt < 4; ++qt)
            Qf[qt] = conv_frag(pkQ[0][qt][0], pkQ[0][qt][1], pkQ[1][qt][0], pkQ[1][qt][1], abase, selhi);
        f32x4 st[4][4];
        #pragma unroll
        for (int kt = 0; kt < 4; ++kt) {
            const bfv8 kf = conv_frag(pkK[0][kt][0], pkK[0][kt][1], pkK[1][kt][0], pkK[1][kt][1], abase, selhi);
            #pragma unroll
            for (int qt = 0; qt < 4; ++qt) {
                f32x4 z{};
                st[kt][qt] = MFMA(kf, Qf[qt], z);
            }
        }

        // ---- softmax per query (qt,lr): reduce over kt,r and lg-groups ----
        float rinv[4];
        #pragma unroll
        for (int qt = 0; qt < 4; ++qt) {
            float mx = -1e30f;
            #pragma unroll
            for (int kt = 0; kt < 4; ++kt)
                #pragma unroll
                for (int r = 0; r < 4; ++r) mx = fmaxf(mx, st[kt][qt][r]);
            mx = fmaxf(mx, __shfl_xor(mx, 16, 64));
            mx = fmaxf(mx, __shfl_xor(mx, 32, 64));
            float sum = 0.f;
            #pragma unroll
            for (int kt = 0; kt < 4; ++kt)
                #pragma unroll
                for (int r = 0; r < 4; ++r) { st[kt][qt][r] = __expf(st[kt][qt][r] - mx); sum += st[kt][qt][r]; }
            sum += __shfl_xor(sum, 16, 64);
            sum += __shfl_xor(sum, 32, 64);
            rinv[qt] = 1.f / sum;
        }
        u32 pkP[4][4][2];   // [qt][kt][p]
        #pragma unroll
        for (int qt = 0; qt < 4; ++qt)
            #pragma unroll
            for (int kt = 0; kt < 4; ++kt)
                #pragma unroll
                for (int p = 0; p < 2; ++p)
                    pkP[qt][kt][p] = pkbf(st[kt][qt][2 * p] * rinv[qt], st[kt][qt][2 * p + 1] * rinv[qt]);

        // ---- PV: O[q][hd] = P @ V ----
        bfv8 Vf[2][2];
        #pragma unroll
        for (int ks = 0; ks < 2; ++ks)
            #pragma unroll
            for (int hdt = 0; hdt < 2; ++hdt)
                Vf[ks][hdt] = conv_frag(pkV[2 * ks][hdt][0], pkV[2 * ks][hdt][1],
                                        pkV[2 * ks + 1][hdt][0], pkV[2 * ks + 1][hdt][1], abase, selhi);
        #pragma unroll
        for (int qt = 0; qt < 4; ++qt) {
            bfv8 pf0 = conv_frag(pkP[qt][0][0], pkP[qt][0][1], pkP[qt][1][0], pkP[qt][1][1], abase, selhi);
            bfv8 pf1 = conv_frag(pkP[qt][2][0], pkP[qt][2][1], pkP[qt][3][0], pkP[qt][3][1], abase, selhi);
            f32x4 o0{}, o1{};
            o0 = MFMA(pf0, Vf[0][0], o0);
            o0 = MFMA(pf1, Vf[1][0], o0);
            o1 = MFMA(pf0, Vf[0][1], o1);
            o1 = MFMA(pf1, Vf[1][1], o1);
            opk[hl][qt][0][0] = pkbf(o0[0], o0[1]);
            opk[hl][qt][0][1] = pkbf(o0[2], o0[3]);
            opk[hl][qt][1][0] = pkbf(o1[0], o1[1]);
            opk[hl][qt][1][1] = pkbf(o1[2], o1[3]);
        }
    }

    __syncthreads();   // barrier 2: all waves done reading sX (x data)

    // ---- write O into sX (dead): row q, col h*32+hdt*16+lr ----
    #pragma unroll
    for (int hl = 0; hl < 3; ++hl)
        #pragma unroll
        for (int qt = 0; qt < 4; ++qt)
            #pragma unroll
            for (int hdt = 0; hdt < 2; ++hdt)
                #pragma unroll
                for (int p = 0; p < 2; ++p) {
                    const u32 u = opk[hl][qt][hdt][p];
                    const int row0 = qt * 16 + lg * 4 + 2 * p;
                    const int col  = (wv * 3 + hl) * 32 + hdt * 16 + lr;
                    unsigned short lo = (unsigned short)(u & 0xffff);
                    unsigned short hi = (unsigned short)(u >> 16);
                    sX[row0 * XW_LD + col]       = *(__bf16*)&lo;
                    sX[(row0 + 1) * XW_LD + col] = *(__bf16*)&hi;
                }
    __syncthreads();   // barrier 3

    // ---- projection: Out = O(64x384) @ Wp + b; wave = 6 n-tiles x 4 m-tiles ----
    const int nb = wv * 96;
    f32x4 acc[4][6];
    {
        const __bf16* bp = wprojT + (size_t)(nb + lr) * 384 + k8;
        #pragma unroll
        for (int m = 0; m < 4; ++m)
            #pragma unroll
            for (int nt = 0; nt < 6; ++nt) acc[m][nt] = f32x4{0,0,0,0};
        #pragma unroll 2
        for (int kk = 0; kk < 12; ++kk) {
            bfv8 bfr[6];
            #pragma unroll
            for (int nt = 0; nt < 6; ++nt)
                bfr[nt] = *(const bfv8*)(bp + (size_t)nt * 16 * 384 + kk * 32);
            #pragma unroll
            for (int m = 0; m < 4; ++m) {
                const bfv8 af = *(const bfv8*)&sX[(m * 16 + lr) * XW_LD + kk * 32 + k8];
                #pragma unroll
                for (int nt = 0; nt < 6; ++nt)
                    acc[m][nt] = MFMA(af, bfr[nt], acc[m][nt]);
            }
        }
    }
    float bpj[6];
    #pragma unroll
    for (int nt = 0; nt < 6; ++nt) bpj[nt] = b_proj[nb + nt * 16 + lr];

    // ---- coalesced output: stage 32 rows (f32) in sX, store full 1536B rows ----
    __syncthreads();   // barrier 4: all proj reads of sX complete
    float* sF = (float*)sX;            // 32 rows x 384 f32 = 49152 B <= 50176
    float* ob = out + gbase;
    #pragma unroll
    for (int half = 0; half < 2; ++half) {
        #pragma unroll
        for (int mm = 0; mm < 2; ++mm) {
            const int m = half * 2 + mm;
            #pragma unroll
            for (int r = 0; r < 4; ++r) {
                const int row = mm * 16 + lg * 4 + r;   // 0..31 within half
                #pragma unroll
                for (int nt = 0; nt < 6; ++nt)
                    sF[row * 384 + nb + nt * 16 + lr] = acc[m][nt][r] + bpj[nt];
            }
        }
        __syncthreads();   // staging visible to all
        for (int i = tid; i < 32 * 96; i += 256) {
            const int row = i / 96;
            const int c4  = (i - row * 96) * 4;
            const int t   = half * 32 + row;
            const float4 v = *(const float4*)&sF[row * 384 + c4];
            *(float4*)(ob + (size_t)((t >> 3) * 64 + (t & 7)) * 384 + c4) = v;
        }
        if (half == 0) __syncthreads();   // stores done before half-1 staging
    }
}

extern "C" void kernel_launch(void* const* d_in, const int* in_sizes, int n_in,
                              void* d_out, int out_size, void* d_ws, size_t ws_size,
                              hipStream_t stream)
{
    const float* x      = (const float*)d_in[0];
    const float* w_qkv  = (const float*)d_in[1];
    const float* b_qkv  = (const float*)d_in[2];
    const float* w_proj = (const float*)d_in[3];
    const float* b_proj = (const float*)d_in[4];
    float* out = (float*)d_out;

    unsigned short* qT = (unsigned short*)d_ws;
    unsigned short* pT = qT + 1152 * 384;

    const int NPREP = 1152 * 384 + 384 * 384;
    prep_weights<<<(NPREP + 255) / 256, 256, 0, stream>>>(w_qkv, w_proj, qT, pT);
    win_attn<<<2048, 256, 0, stream>>>(x, b_qkv, b_proj, qT, pT, out);
}

// Round 12
// 385.119 us; speedup vs baseline: 1.0224x; 1.0224x over previous
//
#include <hip/hip_runtime.h>
#include <hip/hip_bf16.h>

typedef __bf16 bfv8 __attribute__((ext_vector_type(8)));
typedef float f32x4 __attribute__((ext_vector_type(4)));
typedef float fv4 __attribute__((ext_vector_type(4)));   // true vector type for nontemporal builtins
typedef unsigned int u32;

#define MFMA(a,b,c) __builtin_amdgcn_mfma_f32_16x16x32_bf16((a),(b),(c),0,0,0)

constexpr int XW_LD = 392;   // 384+8 pad

// Transposed bf16 weights: qT[col][k] = w_qkv[k][col], pT[col][k] = w_proj[k][col]
__global__ __launch_bounds__(256)
void prep_weights(const float* __restrict__ w_qkv, const float* __restrict__ w_proj,
                  unsigned short* __restrict__ qT, unsigned short* __restrict__ pT)
{
    int i = blockIdx.x * 256 + threadIdx.x;
    const int NQ = 1152 * 384;
    if (i < NQ) {
        int c = i / 384, k = i - c * 384;
        __bf16 h = (__bf16)w_qkv[k * 1152 + c];
        qT[i] = *(unsigned short*)&h;
    } else {
        int j = i - NQ;
        if (j < 384 * 384) {
            int c = j / 384, k = j - c * 384;
            __bf16 h = (__bf16)w_proj[k * 384 + c];
            pT[j] = *(unsigned short*)&h;
        }
    }
}

__device__ __forceinline__ u32 pkbf(float a, float b) {
    __bf16 x = (__bf16)a, y = (__bf16)b;
    unsigned short lo = *(unsigned short*)&x, hi = *(unsigned short*)&y;
    return ((u32)hi << 16) | lo;
}

// Universal D-frag -> A/B-frag converter (HW-verified rounds 3-10):
// dest lane (lg,lr) dword w <- lane (2*(lg&1)+(w>>1))*16+lr, packed dword (w&1),
// tile pair selected by lg&2.
__device__ __forceinline__ bfv8 conv_frag(u32 p00, u32 p01, u32 p10, u32 p11,
                                          int abase, bool selhi)
{
    union { u32 u[4]; bfv8 v; } cv;
    #pragma unroll
    for (int w = 0; w < 4; ++w) {
        const int addr = abase + (w >> 1) * 64;
        const int lo_ = __builtin_amdgcn_ds_bpermute(addr, (int)((w & 1) ? p01 : p00));
        const int hi_ = __builtin_amdgcn_ds_bpermute(addr, (int)((w & 1) ? p11 : p10));
        cv.u[w] = (u32)(selhi ? hi_ : lo_);
    }
    return cv.v;
}

// One WG (256 thr = 4 waves) per 8x8 window; wave owns 3 heads end-to-end.
// R10 base + WEIGHT-L2-RESIDENCY theory: the x-stream (400MB R+W) was evicting
// the 1.2MB weight set from the 4MB per-XCD L2, forcing 2.4GB of per-dispatch
// weight reads to L3 (~500cyc exposed per kk step = the ~385us plateau).
// Fix: non-temporal x loads + out stores (no L2 allocate), unroll 6 for deeper
// weight-load lookahead, bias loads hoisted off the pack critical path.
__global__ __launch_bounds__(256, 3)
void win_attn(const float* __restrict__ x,
              const float* __restrict__ b_qkv,
              const float* __restrict__ b_proj,
              const unsigned short* __restrict__ qT_,
              const unsigned short* __restrict__ pT_,
              float* __restrict__ out)
{
    __shared__ __bf16 sX[64 * XW_LD];   // 50176 B -> 3 WG/CU

    const __bf16* wqkvT  = (const __bf16*)qT_;
    const __bf16* wprojT = (const __bf16*)pT_;

    const int wid  = blockIdx.x;
    const int bb   = wid >> 6;
    const int wy   = (wid >> 3) & 7;
    const int wx   = wid & 7;
    const int tid  = threadIdx.x;
    const int lane = tid & 63;
    const int wv   = tid >> 6;          // wave 0..3
    const int lr   = lane & 15;
    const int lg   = lane >> 4;
    const int k8   = lg * 8;

    const size_t gbase = ((size_t)(bb * 64 + wy * 8) * 64 + wx * 8) * 384;

    // ---- stage x window -> sX bf16 (non-temporal: don't evict weights from L2) ----
    {
        const float* xb = x + gbase;
        for (int i = tid; i < 64 * 96; i += 256) {
            int t  = i / 96;
            int c4 = (i - t * 96) * 4;
            const fv4 v = __builtin_nontemporal_load(
                (const fv4*)(xb + (size_t)((t >> 3) * 64 + (t & 7)) * 384 + c4));
            *(uint2*)&sX[t * XW_LD + c4] = make_uint2(pkbf(v.x, v.y), pkbf(v.z, v.w));
        }
    }
    __syncthreads();   // barrier 1

    const int   abase = ((lg & 1) * 32 + lr) * 4;
    const bool  selhi = (lg & 2) != 0;
    const float SC    = 0.17677669529663687f;   // 32^-0.5

    u32 opk[3][4][2][2];   // fully-static indices -> registers

    #pragma unroll
    for (int hl = 0; hl < 3; ++hl) {
        const int h  = wv * 3 + hl;
        const int cQ = h * 32, cK = cQ + 384, cV = cQ + 768;
        const __bf16* xp = &sX[lr * XW_LD + k8];

        // hoist ALL bias loads off the pack critical path
        float bQ0[2][4], bK0[2][4], bV0[2];
        #pragma unroll
        for (int hdt = 0; hdt < 2; ++hdt) {
            #pragma unroll
            for (int r = 0; r < 4; ++r) {
                bQ0[hdt][r] = b_qkv[cQ + hdt * 16 + lg * 4 + r];
                bK0[hdt][r] = b_qkv[cK + hdt * 16 + lg * 4 + r];
            }
            bV0[hdt] = b_qkv[cV + hdt * 16 + lr];
        }

        u32 pkQ[2][4][2], pkK[2][4][2], pkV[4][2][2];

        // ---- pass 1: Q^T = mfma(Wq-frag, x-frag), swapped ----
        {
            f32x4 acc[2][4];
            #pragma unroll
            for (int a = 0; a < 2; ++a)
                #pragma unroll
                for (int b = 0; b < 4; ++b) acc[a][b] = f32x4{0,0,0,0};
            const __bf16* wp = wqkvT + (size_t)(cQ + lr) * 384 + k8;
            #pragma unroll 6
            for (int kk = 0; kk < 12; ++kk) {
                bfv8 xf[4], wf[2];
                #pragma unroll
                for (int t4 = 0; t4 < 4; ++t4) xf[t4] = *(const bfv8*)(xp + t4 * 16 * XW_LD + kk * 32);
                #pragma unroll
                for (int hdt = 0; hdt < 2; ++hdt) wf[hdt] = *(const bfv8*)(wp + (size_t)hdt * 16 * 384 + kk * 32);
                #pragma unroll
                for (int hdt = 0; hdt < 2; ++hdt)
                    #pragma unroll
                    for (int t4 = 0; t4 < 4; ++t4)
                        acc[hdt][t4] = MFMA(wf[hdt], xf[t4], acc[hdt][t4]);   // Q^T[hd][tok]
            }
            #pragma unroll
            for (int hdt = 0; hdt < 2; ++hdt)
                #pragma unroll
                for (int t4 = 0; t4 < 4; ++t4) {
                    pkQ[hdt][t4][0] = pkbf((acc[hdt][t4][0] + bQ0[hdt][0]) * SC, (acc[hdt][t4][1] + bQ0[hdt][1]) * SC);
                    pkQ[hdt][t4][1] = pkbf((acc[hdt][t4][2] + bQ0[hdt][2]) * SC, (acc[hdt][t4][3] + bQ0[hdt][3]) * SC);
                }
        }

        // ---- pass 2: K^T = mfma(Wk-frag, x-frag), swapped ----
        {
            f32x4 acc[2][4];
            #pragma unroll
            for (int a = 0; a < 2; ++a)
                #pragma unroll
                for (int b = 0; b < 4; ++b) acc[a][b] = f32x4{0,0,0,0};
            const __bf16* wp = wqkvT + (size_t)(cK + lr) * 384 + k8;
            #pragma unroll 6
            for (int kk = 0; kk < 12; ++kk) {
                bfv8 xf[4], wf[2];
                #pragma unroll
                for (int t4 = 0; t4 < 4; ++t4) xf[t4] = *(const bfv8*)(xp + t4 * 16 * XW_LD + kk * 32);
                #pragma unroll
                for (int hdt = 0; hdt < 2; ++hdt) wf[hdt] = *(const bfv8*)(wp + (size_t)hdt * 16 * 384 + kk * 32);
                #pragma unroll
                for (int hdt = 0; hdt < 2; ++hdt)
                    #pragma unroll
                    for (int t4 = 0; t4 < 4; ++t4)
                        acc[hdt][t4] = MFMA(wf[hdt], xf[t4], acc[hdt][t4]);   // K^T[hd][tok]
            }
            #pragma unroll
            for (int hdt = 0; hdt < 2; ++hdt)
                #pragma unroll
                for (int t4 = 0; t4 < 4; ++t4) {
                    pkK[hdt][t4][0] = pkbf(acc[hdt][t4][0] + bK0[hdt][0], acc[hdt][t4][1] + bK0[hdt][1]);
                    pkK[hdt][t4][1] = pkbf(acc[hdt][t4][2] + bK0[hdt][2], acc[hdt][t4][3] + bK0[hdt][3]);
                }
        }

        // ---- pass 3: V = mfma(x-frag, Wv-frag), normal ----
        {
            f32x4 acc[4][2];
            #pragma unroll
            for (int a = 0; a < 4; ++a)
                #pragma unroll
                for (int b = 0; b < 2; ++b) acc[a][b] = f32x4{0,0,0,0};
            const __bf16* wp = wqkvT + (size_t)(cV + lr) * 384 + k8;
            #pragma unroll 6
            for (int kk = 0; kk < 12; ++kk) {
                bfv8 xf[4], wf[2];
                #pragma unroll
                for (int t4 = 0; t4 < 4; ++t4) xf[t4] = *(const bfv8*)(xp + t4 * 16 * XW_LD + kk * 32);
                #pragma unroll
                for (int hdt = 0; hdt < 2; ++hdt) wf[hdt] = *(const bfv8*)(wp + (size_t)hdt * 16 * 384 + kk * 32);
                #pragma unroll
                for (int t4 = 0; t4 < 4; ++t4)
                    #pragma unroll
                    for (int hdt = 0; hdt < 2; ++hdt)
                        acc[t4][hdt] = MFMA(xf[t4], wf[hdt], acc[t4][hdt]);   // V[tok][hd]
            }
            #pragma unroll
            for (int hdt = 0; hdt < 2; ++hdt) {
                const float bv = bV0[hdt];
                #pragma unroll
                for (int t4 = 0; t4 < 4; ++t4) {
                    pkV[t4][hdt][0] = pkbf(acc[t4][hdt][0] + bv, acc[t4][hdt][1] + bv);
                    pkV[t4][hdt][1] = pkbf(acc[t4][hdt][2] + bv, acc[t4][hdt][3] + bv);
                }
            }
        }

        // ---- S^T = mfma(K-frag, Q-frag): lane holds S[q=qt*16+lr][key=kt*16+lg*4+r] ----
        bfv8 Qf[4];
        #pragma unroll
        for (int qt = 0; qt < 4; ++qt)
            Qf[qt] = conv_frag(pkQ[0][qt][0], pkQ[0][qt][1], pkQ[1][qt][0], pkQ[1][qt][1], abase, selhi);
        f32x4 st[4][4];
        #pragma unroll
        for (int kt = 0; kt < 4; ++kt) {
            const bfv8 kf = conv_frag(pkK[0][kt][0], pkK[0][kt][1], pkK[1][kt][0], pkK[1][kt][1], abase, selhi);
            #pragma unroll
            for (int qt = 0; qt < 4; ++qt) {
                f32x4 z{};
                st[kt][qt] = MFMA(kf, Qf[qt], z);
            }
        }

        // ---- softmax per query (qt,lr): reduce over kt,r and lg-groups ----
        float rinv[4];
        #pragma unroll
        for (int qt = 0; qt < 4; ++qt) {
            float mx = -1e30f;
            #pragma unroll
            for (int kt = 0; kt < 4; ++kt)
                #pragma unroll
                for (int r = 0; r < 4; ++r) mx = fmaxf(mx, st[kt][qt][r]);
            mx = fmaxf(mx, __shfl_xor(mx, 16, 64));
            mx = fmaxf(mx, __shfl_xor(mx, 32, 64));
            float sum = 0.f;
            #pragma unroll
            for (int kt = 0; kt < 4; ++kt)
                #pragma unroll
                for (int r = 0; r < 4; ++r) { st[kt][qt][r] = __expf(st[kt][qt][r] - mx); sum += st[kt][qt][r]; }
            sum += __shfl_xor(sum, 16, 64);
            sum += __shfl_xor(sum, 32, 64);
            rinv[qt] = 1.f / sum;
        }
        u32 pkP[4][4][2];   // [qt][kt][p]
        #pragma unroll
        for (int qt = 0; qt < 4; ++qt)
            #pragma unroll
            for (int kt = 0; kt < 4; ++kt)
                #pragma unroll
                for (int p = 0; p < 2; ++p)
                    pkP[qt][kt][p] = pkbf(st[kt][qt][2 * p] * rinv[qt], st[kt][qt][2 * p + 1] * rinv[qt]);

        // ---- PV: O[q][hd] = P @ V ----
        bfv8 Vf[2][2];
        #pragma unroll
        for (int ks = 0; ks < 2; ++ks)
            #pragma unroll
            for (int hdt = 0; hdt < 2; ++hdt)
                Vf[ks][hdt] = conv_frag(pkV[2 * ks][hdt][0], pkV[2 * ks][hdt][1],
                                        pkV[2 * ks + 1][hdt][0], pkV[2 * ks + 1][hdt][1], abase, selhi);
        #pragma unroll
        for (int qt = 0; qt < 4; ++qt) {
            bfv8 pf0 = conv_frag(pkP[qt][0][0], pkP[qt][0][1], pkP[qt][1][0], pkP[qt][1][1], abase, selhi);
            bfv8 pf1 = conv_frag(pkP[qt][2][0], pkP[qt][2][1], pkP[qt][3][0], pkP[qt][3][1], abase, selhi);
            f32x4 o0{}, o1{};
            o0 = MFMA(pf0, Vf[0][0], o0);
            o0 = MFMA(pf1, Vf[1][0], o0);
            o1 = MFMA(pf0, Vf[0][1], o1);
            o1 = MFMA(pf1, Vf[1][1], o1);
            opk[hl][qt][0][0] = pkbf(o0[0], o0[1]);
            opk[hl][qt][0][1] = pkbf(o0[2], o0[3]);
            opk[hl][qt][1][0] = pkbf(o1[0], o1[1]);
            opk[hl][qt][1][1] = pkbf(o1[2], o1[3]);
        }
    }

    __syncthreads();   // barrier 2: all waves done reading sX (x data)

    // ---- write O into sX (dead): row q, col h*32+hdt*16+lr ----
    #pragma unroll
    for (int hl = 0; hl < 3; ++hl)
        #pragma unroll
        for (int qt = 0; qt < 4; ++qt)
            #pragma unroll
            for (int hdt = 0; hdt < 2; ++hdt)
                #pragma unroll
                for (int p = 0; p < 2; ++p) {
                    const u32 u = opk[hl][qt][hdt][p];
                    const int row0 = qt * 16 + lg * 4 + 2 * p;
                    const int col  = (wv * 3 + hl) * 32 + hdt * 16 + lr;
                    unsigned short lo = (unsigned short)(u & 0xffff);
                    unsigned short hi = (unsigned short)(u >> 16);
                    sX[row0 * XW_LD + col]       = *(__bf16*)&lo;
                    sX[(row0 + 1) * XW_LD + col] = *(__bf16*)&hi;
                }
    __syncthreads();   // barrier 3

    // ---- projection: Out = O(64x384) @ Wp + b; wave = 6 n-tiles x 4 m-tiles ----
    const int nb = wv * 96;
    float bpj[6];
    #pragma unroll
    for (int nt = 0; nt < 6; ++nt) bpj[nt] = b_proj[nb + nt * 16 + lr];
    f32x4 acc[4][6];
    {
        const __bf16* bp = wprojT + (size_t)(nb + lr) * 384 + k8;
        #pragma unroll
        for (int m = 0; m < 4; ++m)
            #pragma unroll
            for (int nt = 0; nt < 6; ++nt) acc[m][nt] = f32x4{0,0,0,0};
        #pragma unroll 2
        for (int kk = 0; kk < 12; ++kk) {
            bfv8 bfr[6];
            #pragma unroll
            for (int nt = 0; nt < 6; ++nt)
                bfr[nt] = *(const bfv8*)(bp + (size_t)nt * 16 * 384 + kk * 32);
            #pragma unroll
            for (int m = 0; m < 4; ++m) {
                const bfv8 af = *(const bfv8*)&sX[(m * 16 + lr) * XW_LD + kk * 32 + k8];
                #pragma unroll
                for (int nt = 0; nt < 6; ++nt)
                    acc[m][nt] = MFMA(af, bfr[nt], acc[m][nt]);
            }
        }
    }

    // ---- coalesced output: stage 32 rows (f32) in sX, store full 1536B rows ----
    __syncthreads();   // barrier 4: all proj reads of sX complete
    float* sF = (float*)sX;            // 32 rows x 384 f32 = 49152 B <= 50176
    float* ob = out + gbase;
    #pragma unroll
    for (int half = 0; half < 2; ++half) {
        #pragma unroll
        for (int mm = 0; mm < 2; ++mm) {
            const int m = half * 2 + mm;
            #pragma unroll
            for (int r = 0; r < 4; ++r) {
                const int row = mm * 16 + lg * 4 + r;   // 0..31 within half
                #pragma unroll
                for (int nt = 0; nt < 6; ++nt)
                    sF[row * 384 + nb + nt * 16 + lr] = acc[m][nt][r] + bpj[nt];
            }
        }
        __syncthreads();   // staging visible to all
        for (int i = tid; i < 32 * 96; i += 256) {
            const int row = i / 96;
            const int c4  = (i - row * 96) * 4;
            const int t   = half * 32 + row;
            const fv4 v = *(const fv4*)&sF[row * 384 + c4];
            __builtin_nontemporal_store(v, (fv4*)(ob + (size_t)((t >> 3) * 64 + (t & 7)) * 384 + c4));
        }
        if (half == 0) __syncthreads();   // stores done before half-1 staging
    }
}

extern "C" void kernel_launch(void* const* d_in, const int* in_sizes, int n_in,
                              void* d_out, int out_size, void* d_ws, size_t ws_size,
                              hipStream_t stream)
{
    const float* x      = (const float*)d_in[0];
    const float* w_qkv  = (const float*)d_in[1];
    const float* b_qkv  = (const float*)d_in[2];
    const float* w_proj = (const float*)d_in[3];
    const float* b_proj = (const float*)d_in[4];
    float* out = (float*)d_out;

    unsigned short* qT = (unsigned short*)d_ws;
    unsigned short* pT = qT + 1152 * 384;

    const int NPREP = 1152 * 384 + 384 * 384;
    prep_weights<<<(NPREP + 255) / 256, 256, 0, stream>>>(w_qkv, w_proj, qT, pT);
    win_attn<<<2048, 256, 0, stream>>>(x, b_qkv, b_proj, qT, pT, out);
}